// Round 3
// baseline (284.119 us; speedup 1.0000x reference)
//
#include <hip/hip_runtime.h>
#include <hip/hip_bf16.h>
#include <stdint.h>

// Problem constants
#define B_ROWS 32768
#define NUM_IN 1024
#define D_PAD2 1152   // 1064 padded to 18*64 (even # of 64-wide K tiles)
#define HID    2048
#define NPAD   64     // 37 logits padded to 64

typedef __attribute__((ext_vector_type(8))) short bf16x8;
typedef __attribute__((ext_vector_type(4))) float f32x4;
typedef unsigned short ushort_t;

__device__ __forceinline__ unsigned short f2bf(float f){
  union { float f; uint32_t u; } x; x.f = f;
  uint32_t u = x.u;
  return (unsigned short)((u + 0x7FFFu + ((u >> 16) & 1u)) >> 16);
}

__device__ __forceinline__ void gload16(const void* g, void* l){
  __builtin_amdgcn_global_load_lds((const __attribute__((address_space(1))) void*)g,
                                   (__attribute__((address_space(3))) void*)l, 16, 0, 0);
}

// ---------------- discretizer scan (per batch element) ----------------
__device__ __forceinline__ int disc_step(
    float cam0, float cam1, const int a[5],
    float& ac0, float& ac1, float& delta,
    int r[5], bool& dch, int& cam_steps, bool& committed, float& norm)
{
  const int RS[5] = {6, 8, 10, 11, 14};
  norm += committed ? 0.0f : 1.0f;
  bool commit = ((fabsf(cam0) < 1e-5f) && (fabsf(cam1) < 1e-5f)) || (cam_steps >= 6);
  #pragma unroll
  for (int i = 0; i < 5; ++i) commit = commit && (r[i] == a[i]);
  int dac = 0;
  bool modified = commit;
  #pragma unroll
  for (int i = 0; i < 5; ++i){
    bool disc = (!modified) && (r[i] != a[i]);
    if (disc){
      dac = (a[i] == 0) ? (r[i] - 1 + RS[i]) : (a[i] - 1 + RS[i]);
      r[i] = a[i];
      modified = true;
    }
  }
  float d2 = delta * 2.0f;
  // NOTE: reference compares BOTH cam0 and cam1 against ac[:,0] — replicate.
  bool dmask = (!modified) && (!dch) &&
               ((fabsf(cam0 - ac0) > d2) || (fabsf(cam1 - ac0) > d2));
  if (dmask){ dac = 5; delta = fminf(d2, 0.5f); modified = true; }
  if (!modified){
    float sx = (cam0 < ac0) ? -1.0f : 1.0f;
    float sy = (cam1 < ac1) ? -1.0f : 1.0f;
    dac = (sx < 0.0f) ? ((sy < 0.0f) ? 1 : 3) : ((sy < 0.0f) ? 2 : 4);
    ac0 += sx * delta; ac1 += sy * delta;
    delta *= 0.5f;
    dch = true;
    cam_steps += 1;
  }
  committed = committed || commit;
  return dac;
}

__global__ void k_disc(const float* __restrict__ camera, const float* __restrict__ rand_u,
                       const int* __restrict__ afb, const int* __restrict__ alr,
                       const int* __restrict__ ajp, const int* __restrict__ ass,
                       const int* __restrict__ aat,
                       unsigned short* __restrict__ xb, int* __restrict__ tgt)
{
  int row = blockIdx.x * 256 + threadIdx.x;
  if (row >= B_ROWS) return;
  float cam0 = camera[2*row], cam1 = camera[2*row + 1];
  int a[5] = { afb[row], alr[row], ajp[row], ass[row], aat[row] };

  // pass 1: compute norm
  float ac0 = 0.f, ac1 = 0.f, delta = 0.0625f, norm = 0.f;
  int r[5] = {0,0,0,0,0};
  bool dch = false, committed = false; int cam_steps = 0;
  for (int t = 0; t < 20; ++t)
    disc_step(cam0, cam1, a, ac0, ac1, delta, r, dch, cam_steps, committed, norm);

  int rs = (int)(rand_u[row] * norm);
  if (rs > 19) rs = 19;
  if (rs < 0) rs = 0;

  // pass 2: advance rs steps, emit entry state, then step rs for dac
  ac0 = 0.f; ac1 = 0.f; delta = 0.0625f; norm = 0.f;
  r[0]=r[1]=r[2]=r[3]=r[4]=0; dch = false; committed = false; cam_steps = 0;
  for (int t = 0; t < rs; ++t)
    disc_step(cam0, cam1, a, ac0, ac1, delta, r, dch, cam_steps, committed, norm);

  float vec[40];
  #pragma unroll
  for (int j = 0; j < 40; ++j) vec[j] = 0.0f;
  vec[0] = ac0; vec[1] = ac1;
  const int offs[5] = {2, 5, 8, 10, 14};
  #pragma unroll
  for (int i = 0; i < 5; ++i) vec[offs[i] + r[i]] = 1.0f;
  vec[38] = delta; vec[39] = dch ? 1.0f : 0.0f;

  int dac = disc_step(cam0, cam1, a, ac0, ac1, delta, r, dch, cam_steps, committed, norm);
  tgt[row] = dac;

  unsigned short* o = xb + (size_t)row * D_PAD2 + NUM_IN;
  #pragma unroll
  for (int j = 0; j < 40; ++j) o[j] = f2bf(vec[j]);
  // zero-pad cols 1064..1151
  for (int j = 40; j < D_PAD2 - NUM_IN; ++j) o[j] = 0;
}

// ---------------- conversions ----------------
__global__ void k_fc(const float* __restrict__ fc, unsigned short* __restrict__ xb)
{
  int gid = blockIdx.x * 256 + threadIdx.x;     // B*1024/8 = 4194304 total
  int row = gid >> 7;                           // 128 8-elt chunks per row
  int c   = gid & 127;
  const float4* p = (const float4*)(fc + (size_t)row * NUM_IN + c * 8);
  float4 f0 = p[0], f1 = p[1];
  unsigned short o[8] = { f2bf(f0.x), f2bf(f0.y), f2bf(f0.z), f2bf(f0.w),
                          f2bf(f1.x), f2bf(f1.y), f2bf(f1.z), f2bf(f1.w) };
  uint4 pk;
  pk.x = (uint32_t)o[0] | ((uint32_t)o[1] << 16);
  pk.y = (uint32_t)o[2] | ((uint32_t)o[3] << 16);
  pk.z = (uint32_t)o[4] | ((uint32_t)o[5] << 16);
  pk.w = (uint32_t)o[6] | ((uint32_t)o[7] << 16);
  *(uint4*)(xb + (size_t)row * D_PAD2 + c * 8) = pk;
}

__global__ void k_w1t(const float* __restrict__ W1, unsigned short* __restrict__ w1t)
{
  int idx = blockIdx.x * 256 + threadIdx.x;     // over 2048*1152
  if (idx >= HID * D_PAD2) return;
  int n = idx / D_PAD2;
  int k = idx - n * D_PAD2;
  float v = (k < 1064) ? W1[(size_t)k * HID + n] : 0.0f;
  w1t[idx] = f2bf(v);
}

__global__ void k_w2t(const float* __restrict__ W2, unsigned short* __restrict__ w2t)
{
  int idx = blockIdx.x * 256 + threadIdx.x;     // over 64*2048
  if (idx >= NPAD * HID) return;
  int n = idx >> 11;
  int k = idx & (HID - 1);
  float v = (n < 37) ? W2[(size_t)k * 37 + n] : 0.0f;
  w2t[idx] = f2bf(v);
}

// ---------------- GEMM1: 256x256 8-phase + fused W2 projection ----------------
// LDS regions (ushort offsets): even K-tiles in A0/B0, odd in A1/B1.
#define LDS_A0 0
#define LDS_A1 16384
#define LDS_B0 32768
#define LDS_B1 49152

// stage one 128x64 half-tile: 2 x global_load_lds(16B) per thread, 512 threads.
// LDS dest is LINEAR (wave-uniform base + lane*16); the XOR swizzle is realized
// by pre-swizzling the GLOBAL source column chunk (involution, rule #21).
#define STAGE(G, REG, ROW0, KT, HALF) do { \
    const ushort_t* s0_ = (G) + (size_t)((ROW0) + (HALF)*128 + srow) * D_PAD2 + ((KT) << 6) + scol; \
    gload16(s0_, lds + (REG) + (HALF)*8192 + t*8); \
    gload16(s0_ + (size_t)64 * D_PAD2, lds + (REG) + (HALF)*8192 + 4096 + t*8); \
  } while(0)

// fragment reads: byte chunk index = (kk*4+lg) ^ (row&7); row&7 == lr&7 here.
#define LDA_(REG, MH) do { \
    _Pragma("unroll") for (int mi_ = 0; mi_ < 4; ++mi_){ \
      const int row_ = arow_base + (MH)*64 + mi_*16; \
      _Pragma("unroll") for (int kk_ = 0; kk_ < 2; ++kk_) \
        aR[mi_][kk_] = *(const bf16x8*)(lds + (REG) + row_*64 + (((kk_*4+lg)^axor)<<3)); \
    } \
  } while(0)

#define LDB_(REG, NH, BR) do { \
    _Pragma("unroll") for (int ni_ = 0; ni_ < 2; ++ni_){ \
      const int row_ = brow_base + (NH)*32 + ni_*16; \
      _Pragma("unroll") for (int kk_ = 0; kk_ < 2; ++kk_) \
        BR[ni_][kk_] = *(const bf16x8*)(lds + (REG) + row_*64 + (((kk_*4+lg)^axor)<<3)); \
    } \
  } while(0)

#define MMA(MH, NH, BR) do { \
    __builtin_amdgcn_s_setprio(1); \
    _Pragma("unroll") for (int mi_ = 0; mi_ < 4; ++mi_) \
    _Pragma("unroll") for (int ni_ = 0; ni_ < 2; ++ni_) \
    _Pragma("unroll") for (int kk_ = 0; kk_ < 2; ++kk_) \
      acc[(MH)*4+mi_][(NH)*2+ni_] = __builtin_amdgcn_mfma_f32_16x16x32_bf16( \
          aR[mi_][kk_], BR[ni_][kk_], acc[(MH)*4+mi_][(NH)*2+ni_], 0, 0, 0); \
    __builtin_amdgcn_s_setprio(0); \
  } while(0)

#define BAR() __builtin_amdgcn_s_barrier()
#define WAIT_LGKM0() asm volatile("s_waitcnt lgkmcnt(0)" ::: "memory")
#define WAIT_VM6()   asm volatile("s_waitcnt vmcnt(6)" ::: "memory")
#define WAIT_VM0()   asm volatile("s_waitcnt vmcnt(0)" ::: "memory")

__global__ __launch_bounds__(512, 2) void k_gemm1(const ushort_t* __restrict__ xb,
                                                  const ushort_t* __restrict__ w1t,
                                                  const ushort_t* __restrict__ w2t,
                                                  const float* __restrict__ b1,
                                                  float* __restrict__ pbuf)
{
  __shared__ ushort_t lds[65536];   // 128 KiB
  const int t = threadIdx.x;        // 0..511
  const int lane = t & 63;
  const int wid = t >> 6, wm = wid >> 2, wn = wid & 3;
  const int lr = lane & 15, lg = lane >> 4;

  // XCD-aware swizzle (nwg=1024 divisible by 8 -> bijective).
  const int bid = blockIdx.x;
  const int swz = (bid & 7) * 128 + (bid >> 3);
  const int brow = (swz >> 3) << 8;   // 128 row tiles of 256
  const int bcol = (swz & 7) << 8;    // 8 col tiles of 256

  // staging coords
  const int srow = t >> 3;                          // 0..63
  const int scol = ((t & 7) ^ (srow & 7)) << 3;     // pre-swizzled source chunk

  // fragment coords
  const int axor = lr & 7;
  const int arow_base = wm*128 + lr;
  const int brow_base = wn*64 + lr;

  f32x4 acc[8][4] = {};
  bf16x8 aR[4][2], bR0[2][2], bR1[2][2];

  // ---- prologue: tile0 -> buf0 (4 halves), tile1 -> buf1 (B h0,h1 + A h0)
  STAGE(xb,  LDS_A0, brow, 0, 0);  STAGE(xb,  LDS_A0, brow, 0, 1);
  STAGE(w1t, LDS_B0, bcol, 0, 0);  STAGE(w1t, LDS_B0, bcol, 0, 1);
  STAGE(w1t, LDS_B1, bcol, 1, 0);  STAGE(w1t, LDS_B1, bcol, 1, 1);
  STAGE(xb,  LDS_A1, brow, 1, 0);
  WAIT_VM6();            // 14 loads issued, <=6 outstanding -> tile0 landed
  BAR();

  for (int i = 0; i < 9; ++i){
    const int c1 = 2*i + 1;
    const int n0 = (2*i + 2 <= 17) ? 2*i + 2 : 16;  // clamp: re-stages same data, benign
    const int n1 = (2*i + 3 <= 17) ? 2*i + 3 : 17;

    // ph1: read A0(mh0) + ALL B0; stage A1.h1 (tile c1)
    LDA_(LDS_A0, 0); LDB_(LDS_B0, 0, bR0); LDB_(LDS_B0, 1, bR1);
    STAGE(xb, LDS_A1, brow, c1, 1);
    BAR(); WAIT_LGKM0();
    MMA(0, 0, bR0);
    BAR();
    // ph2: stage B0.h0 (tile n0; B0 region free after ph1)
    STAGE(w1t, LDS_B0, bcol, n0, 0);
    BAR();
    MMA(0, 1, bR1);
    BAR();
    // ph3: read A0(mh1); stage B0.h1
    LDA_(LDS_A0, 1);
    STAGE(w1t, LDS_B0, bcol, n0, 1);
    BAR(); WAIT_LGKM0();
    MMA(1, 0, bR0);
    BAR();
    // ph4: stage A0.h0 (A0 free after ph3); counted vmcnt -> tile c1 landed
    STAGE(xb, LDS_A0, brow, n0, 0);
    WAIT_VM6();
    BAR();
    MMA(1, 1, bR1);
    BAR();
    // ph5: read A1(mh0) + ALL B1 (tile c1); stage A0.h1
    LDA_(LDS_A1, 0); LDB_(LDS_B1, 0, bR0); LDB_(LDS_B1, 1, bR1);
    STAGE(xb, LDS_A0, brow, n0, 1);
    BAR(); WAIT_LGKM0();
    MMA(0, 0, bR0);
    BAR();
    // ph6: stage B1.h0 (tile n1; B1 free after ph5)
    STAGE(w1t, LDS_B1, bcol, n1, 0);
    BAR();
    MMA(0, 1, bR1);
    BAR();
    // ph7: read A1(mh1); stage B1.h1
    LDA_(LDS_A1, 1);
    STAGE(w1t, LDS_B1, bcol, n1, 1);
    BAR(); WAIT_LGKM0();
    MMA(1, 0, bR0);
    BAR();
    // ph8: stage A1.h0 (A1 free after ph7); counted vmcnt -> tile n0 landed
    STAGE(xb, LDS_A1, brow, n1, 0);
    WAIT_VM6();
    BAR();
    MMA(1, 1, bR1);
    BAR();
  }

  // ---- fused epilogue: silu -> LDS h-tile -> mini-GEMM vs W2 chunk -> partials
  // Drain pending (clamped) prefetches before reusing LDS, then sync.
  WAIT_VM0();
  BAR();

  // bias for this wave's columns
  float b1v[4];
  #pragma unroll
  for (int ni = 0; ni < 4; ++ni) b1v[ni] = b1[bcol + wn*64 + ni*16 + lr];

  // silu + pack to bf16; scatter into LDS as [row 256][col 256] with chunk-XOR swizzle
  #pragma unroll
  for (int mi = 0; mi < 8; ++mi){
    #pragma unroll
    for (int ni = 0; ni < 4; ++ni){
      const int col = wn*64 + ni*16 + lr;
      #pragma unroll
      for (int i2 = 0; i2 < 4; ++i2){
        const int row = wm*128 + mi*16 + lg*4 + i2;
        float v = acc[mi][ni][i2] + b1v[ni];
        float s = v / (1.0f + __expf(-v));     // silu
        const int chunk = (col >> 3) ^ (row & 7);
        lds[row*256 + chunk*8 + (col & 7)] = f2bf(s);
      }
    }
  }
  __syncthreads();

  // mini-GEMM: partial[r][n] = hTile[r][:256] @ W2chunk[:256][n], n in [0,64)
  // Each wave owns 32 rows. B-frags read direct from global w2t (L1/L2-hot).
  const int rb = wid * 32;
  f32x4 acc2[2][4] = {};
  #pragma unroll
  for (int ks = 0; ks < 8; ++ks){
    bf16x8 a2[2], b2f[4];
    #pragma unroll
    for (int m = 0; m < 2; ++m){
      const int row = rb + m*16 + lr;
      a2[m] = *(const bf16x8*)(lds + row*256 + (((ks*4+lg) ^ (lr & 7)) << 3));
    }
    #pragma unroll
    for (int ni = 0; ni < 4; ++ni)
      b2f[ni] = *(const bf16x8*)(w2t + (size_t)(ni*16 + lr) * HID + bcol + ks*32 + lg*8);
    #pragma unroll
    for (int m = 0; m < 2; ++m)
      #pragma unroll
      for (int ni = 0; ni < 4; ++ni)
        acc2[m][ni] = __builtin_amdgcn_mfma_f32_16x16x32_bf16(a2[m], b2f[ni], acc2[m][ni], 0, 0, 0);
  }

  // store partials: pbuf[cb][row][col]  (each store instr covers full 64B lines)
  const int cb = bcol >> 8;
  #pragma unroll
  for (int m = 0; m < 2; ++m)
    #pragma unroll
    for (int ni = 0; ni < 4; ++ni)
      #pragma unroll
      for (int i2 = 0; i2 < 4; ++i2){
        const int r = brow + rb + m*16 + lg*4 + i2;
        pbuf[((size_t)cb << 21) + ((size_t)r << 6) + ni*16 + lr] = acc2[m][ni][i2];
      }
}

// ---------------- reduce: sum partials + b2 -> log-softmax -> NLL ----------------
__global__ __launch_bounds__(256) void k_red(const float* __restrict__ pbuf,
                                             const float* __restrict__ b2,
                                             const int* __restrict__ tgt,
                                             float* __restrict__ loss)
{
  const int lane = threadIdx.x & 63, w = threadIdx.x >> 6;
  const int row0 = blockIdx.x * 128 + w * 32;
  const float bias = (lane < 37) ? b2[lane] : 0.0f;
  for (int i = 0; i < 32; ++i){
    const int r = row0 + i;
    float s = 0.0f;
    #pragma unroll
    for (int cb = 0; cb < 8; ++cb)
      s += pbuf[((size_t)cb << 21) + ((size_t)r << 6) + lane];
    float x = (lane < 37) ? (s + bias) : -1e30f;
    float m = x;
    #pragma unroll
    for (int off = 1; off < 64; off <<= 1) m = fmaxf(m, __shfl_xor(m, off, 64));
    float e = __expf(x - m);                 // padded lanes underflow to 0
    float se = e;
    #pragma unroll
    for (int off = 1; off < 64; off <<= 1) se += __shfl_xor(se, off, 64);
    const int tg = tgt[r];
    const float pick = __shfl(x, tg, 64);
    if (lane == 0) loss[r] = m + __logf(se) - pick;
  }
}

// ---------------- launch ----------------
extern "C" void kernel_launch(void* const* d_in, const int* in_sizes, int n_in,
                              void* d_out, int out_size, void* d_ws, size_t ws_size,
                              hipStream_t stream)
{
  (void)in_sizes; (void)n_in; (void)out_size; (void)ws_size;
  const float* fc  = (const float*)d_in[0];
  const float* cam = (const float*)d_in[1];
  const float* ru  = (const float*)d_in[2];
  const float* W1  = (const float*)d_in[3];
  const float* b1  = (const float*)d_in[4];
  const float* W2  = (const float*)d_in[5];
  const float* b2  = (const float*)d_in[6];
  const int* afb = (const int*)d_in[7];
  const int* alr = (const int*)d_in[8];
  const int* ajp = (const int*)d_in[9];
  const int* ass = (const int*)d_in[10];
  const int* aat = (const int*)d_in[11];
  float* loss = (float*)d_out;

  // workspace layout (bytes):
  // xb   : 32768 x 1152 bf16 = 75,497,472
  // w1t  : 2048 x 1152 bf16  =  4,718,592
  // w2t  : 64 x 2048 bf16    =    262,144
  // tgt  : 32768 int32       =    131,072
  // pbuf : 8 x 32768 x 64 f32 = 67,108,864   (total ~140.9 MiB)
  char* ws = (char*)d_ws;
  unsigned short* xb  = (unsigned short*)(ws);
  unsigned short* w1t = (unsigned short*)(ws + 75497472);
  unsigned short* w2t = (unsigned short*)(ws + 80216064);
  int*            tgt = (int*)           (ws + 80478208);
  float*          pbuf= (float*)         (ws + 80609280);

  k_fc  <<<16384, 256, 0, stream>>>(fc, xb);
  k_w1t <<<(HID * D_PAD2 + 255) / 256, 256, 0, stream>>>(W1, w1t);
  k_w2t <<<(NPAD * HID + 255) / 256, 256, 0, stream>>>(W2, w2t);
  k_disc<<<(B_ROWS + 255) / 256, 256, 0, stream>>>(cam, ru, afb, alr, ajp, ass, aat, xb, tgt);

  k_gemm1<<<(B_ROWS/256) * (HID/256), 512, 0, stream>>>(xb, w1t, w2t, b1, pbuf);
  k_red  <<<B_ROWS / 128, 256, 0, stream>>>(pbuf, b2, tgt, loss);
}

// Round 4
// 275.632 us; speedup vs baseline: 1.0308x; 1.0308x over previous
//
#include <hip/hip_runtime.h>
#include <hip/hip_bf16.h>
#include <stdint.h>

// Problem constants
#define B_ROWS 32768
#define NUM_IN 1024
#define D_PAD2 1088   // 1064 padded to 17*64 K-tiles (8 dbuf iterations + 1 tail tile)
#define HID    2048
#define NPAD   64     // 37 logits padded to 64

typedef __attribute__((ext_vector_type(8))) short bf16x8;
typedef __attribute__((ext_vector_type(4))) float f32x4;
typedef unsigned short ushort_t;

__device__ __forceinline__ unsigned short f2bf(float f){
  union { float f; uint32_t u; } x; x.f = f;
  uint32_t u = x.u;
  return (unsigned short)((u + 0x7FFFu + ((u >> 16) & 1u)) >> 16);
}

__device__ __forceinline__ void gload16(const void* g, void* l){
  __builtin_amdgcn_global_load_lds((const __attribute__((address_space(1))) void*)g,
                                   (__attribute__((address_space(3))) void*)l, 16, 0, 0);
}

// ---------------- discretizer scan (per batch element) ----------------
__device__ __forceinline__ int disc_step(
    float cam0, float cam1, const int a[5],
    float& ac0, float& ac1, float& delta,
    int r[5], bool& dch, int& cam_steps, bool& committed, float& norm)
{
  const int RS[5] = {6, 8, 10, 11, 14};
  norm += committed ? 0.0f : 1.0f;
  bool commit = ((fabsf(cam0) < 1e-5f) && (fabsf(cam1) < 1e-5f)) || (cam_steps >= 6);
  #pragma unroll
  for (int i = 0; i < 5; ++i) commit = commit && (r[i] == a[i]);
  int dac = 0;
  bool modified = commit;
  #pragma unroll
  for (int i = 0; i < 5; ++i){
    bool disc = (!modified) && (r[i] != a[i]);
    if (disc){
      dac = (a[i] == 0) ? (r[i] - 1 + RS[i]) : (a[i] - 1 + RS[i]);
      r[i] = a[i];
      modified = true;
    }
  }
  float d2 = delta * 2.0f;
  // NOTE: reference compares BOTH cam0 and cam1 against ac[:,0] — replicate.
  bool dmask = (!modified) && (!dch) &&
               ((fabsf(cam0 - ac0) > d2) || (fabsf(cam1 - ac0) > d2));
  if (dmask){ dac = 5; delta = fminf(d2, 0.5f); modified = true; }
  if (!modified){
    float sx = (cam0 < ac0) ? -1.0f : 1.0f;
    float sy = (cam1 < ac1) ? -1.0f : 1.0f;
    dac = (sx < 0.0f) ? ((sy < 0.0f) ? 1 : 3) : ((sy < 0.0f) ? 2 : 4);
    ac0 += sx * delta; ac1 += sy * delta;
    delta *= 0.5f;
    dch = true;
    cam_steps += 1;
  }
  committed = committed || commit;
  return dac;
}

// ---------------- fused prep: fc convert | W1^T | W2^T | discretizer ----------------
// block ranges: [0,16384) fc ; [16384,25088) w1t ; [25088,25600) w2t ; [25600,25728) disc
__global__ void k_prep(const float* __restrict__ fc, const float* __restrict__ W1,
                       const float* __restrict__ W2,
                       const float* __restrict__ camera, const float* __restrict__ rand_u,
                       const int* __restrict__ afb, const int* __restrict__ alr,
                       const int* __restrict__ ajp, const int* __restrict__ ass,
                       const int* __restrict__ aat,
                       unsigned short* __restrict__ xb, unsigned short* __restrict__ w1t,
                       unsigned short* __restrict__ w2t, int* __restrict__ tgt)
{
  const int b = blockIdx.x;
  const int tid = threadIdx.x;
  if (b < 16384){
    // fc f32 -> bf16, rows of 1024 into stride-1088 xb
    int gid = b * 256 + tid;
    int row = gid >> 7;
    int c   = gid & 127;
    const float4* p = (const float4*)(fc + (size_t)row * NUM_IN + c * 8);
    float4 f0 = p[0], f1 = p[1];
    uint4 pk;
    pk.x = (uint32_t)f2bf(f0.x) | ((uint32_t)f2bf(f0.y) << 16);
    pk.y = (uint32_t)f2bf(f0.z) | ((uint32_t)f2bf(f0.w) << 16);
    pk.z = (uint32_t)f2bf(f1.x) | ((uint32_t)f2bf(f1.y) << 16);
    pk.w = (uint32_t)f2bf(f1.z) | ((uint32_t)f2bf(f1.w) << 16);
    *(uint4*)(xb + (size_t)row * D_PAD2 + c * 8) = pk;
    return;
  }
  if (b < 25088){
    int idx = (b - 16384) * 256 + tid;        // over 2048*1088
    int n = idx / D_PAD2;
    int k = idx - n * D_PAD2;
    float v = (k < 1064) ? W1[(size_t)k * HID + n] : 0.0f;
    w1t[idx] = f2bf(v);
    return;
  }
  if (b < 25600){
    int idx = (b - 25088) * 256 + tid;        // over 64*2048
    int n = idx >> 11;
    int k = idx & (HID - 1);
    float v = (n < 37) ? W2[(size_t)k * 37 + n] : 0.0f;
    w2t[idx] = f2bf(v);
    return;
  }
  // discretizer
  int row = (b - 25600) * 256 + tid;
  float cam0 = camera[2*row], cam1 = camera[2*row + 1];
  int a[5] = { afb[row], alr[row], ajp[row], ass[row], aat[row] };

  float ac0 = 0.f, ac1 = 0.f, delta = 0.0625f, norm = 0.f;
  int r[5] = {0,0,0,0,0};
  bool dch = false, committed = false; int cam_steps = 0;
  for (int t = 0; t < 20; ++t)
    disc_step(cam0, cam1, a, ac0, ac1, delta, r, dch, cam_steps, committed, norm);

  int rs = (int)(rand_u[row] * norm);
  if (rs > 19) rs = 19;
  if (rs < 0) rs = 0;

  ac0 = 0.f; ac1 = 0.f; delta = 0.0625f; norm = 0.f;
  r[0]=r[1]=r[2]=r[3]=r[4]=0; dch = false; committed = false; cam_steps = 0;
  for (int t = 0; t < rs; ++t)
    disc_step(cam0, cam1, a, ac0, ac1, delta, r, dch, cam_steps, committed, norm);

  float vec[40];
  #pragma unroll
  for (int j = 0; j < 40; ++j) vec[j] = 0.0f;
  vec[0] = ac0; vec[1] = ac1;
  const int offs[5] = {2, 5, 8, 10, 14};
  #pragma unroll
  for (int i = 0; i < 5; ++i) vec[offs[i] + r[i]] = 1.0f;
  vec[38] = delta; vec[39] = dch ? 1.0f : 0.0f;

  int dac = disc_step(cam0, cam1, a, ac0, ac1, delta, r, dch, cam_steps, committed, norm);
  tgt[row] = dac;

  unsigned short* o = xb + (size_t)row * D_PAD2 + NUM_IN;
  #pragma unroll
  for (int j = 0; j < 40; ++j) o[j] = f2bf(vec[j]);
  #pragma unroll
  for (int j = 40; j < 64; ++j) o[j] = 0;   // pad cols 1064..1087
}

// ---------------- GEMM1: 256x256 8-phase + fused W2 projection ----------------
#define LDS_A0 0
#define LDS_A1 16384
#define LDS_B0 32768
#define LDS_B1 49152

#define STAGE(G, REG, ROW0, KT, HALF) do { \
    const ushort_t* s0_ = (G) + (size_t)((ROW0) + (HALF)*128 + srow) * D_PAD2 + ((KT) << 6) + scol; \
    gload16(s0_, lds + (REG) + (HALF)*8192 + t*8); \
    gload16(s0_ + (size_t)64 * D_PAD2, lds + (REG) + (HALF)*8192 + 4096 + t*8); \
  } while(0)

#define LDA_(REG, MH) do { \
    _Pragma("unroll") for (int mi_ = 0; mi_ < 4; ++mi_){ \
      const int row_ = arow_base + (MH)*64 + mi_*16; \
      _Pragma("unroll") for (int kk_ = 0; kk_ < 2; ++kk_) \
        aR[mi_][kk_] = *(const bf16x8*)(lds + (REG) + row_*64 + (((kk_*4+lg)^axor)<<3)); \
    } \
  } while(0)

#define LDB_(REG, NH, BR) do { \
    _Pragma("unroll") for (int ni_ = 0; ni_ < 2; ++ni_){ \
      const int row_ = brow_base + (NH)*32 + ni_*16; \
      _Pragma("unroll") for (int kk_ = 0; kk_ < 2; ++kk_) \
        BR[ni_][kk_] = *(const bf16x8*)(lds + (REG) + row_*64 + (((kk_*4+lg)^axor)<<3)); \
    } \
  } while(0)

#define MMA(MH, NH, BR) do { \
    __builtin_amdgcn_s_setprio(1); \
    _Pragma("unroll") for (int mi_ = 0; mi_ < 4; ++mi_) \
    _Pragma("unroll") for (int ni_ = 0; ni_ < 2; ++ni_) \
    _Pragma("unroll") for (int kk_ = 0; kk_ < 2; ++kk_) \
      acc[(MH)*4+mi_][(NH)*2+ni_] = __builtin_amdgcn_mfma_f32_16x16x32_bf16( \
          aR[mi_][kk_], BR[ni_][kk_], acc[(MH)*4+mi_][(NH)*2+ni_], 0, 0, 0); \
    __builtin_amdgcn_s_setprio(0); \
  } while(0)

#define BAR() __builtin_amdgcn_s_barrier()
#define WAIT_LGKM0() asm volatile("s_waitcnt lgkmcnt(0)" ::: "memory")
#define WAIT_VM6()   asm volatile("s_waitcnt vmcnt(6)" ::: "memory")
#define WAIT_VM0()   asm volatile("s_waitcnt vmcnt(0)" ::: "memory")

__global__ __launch_bounds__(512, 2) void k_gemm1(const ushort_t* __restrict__ xb,
                                                  const ushort_t* __restrict__ w1t,
                                                  const ushort_t* __restrict__ w2t,
                                                  const float* __restrict__ b1,
                                                  float* __restrict__ pbuf)
{
  __shared__ ushort_t lds[65536];   // 128 KiB
  const int t = threadIdx.x;        // 0..511
  const int lane = t & 63;
  const int wid = t >> 6, wm = wid >> 2, wn = wid & 3;
  const int lr = lane & 15, lg = lane >> 4;

  // XCD-aware swizzle (nwg=1024 divisible by 8 -> bijective).
  const int bid = blockIdx.x;
  const int swz = (bid & 7) * 128 + (bid >> 3);
  const int brow = (swz >> 3) << 8;   // 128 row tiles of 256
  const int bcol = (swz & 7) << 8;    // 8 col tiles of 256

  // staging coords
  const int srow = t >> 3;                          // 0..63
  const int scol = ((t & 7) ^ (srow & 7)) << 3;     // pre-swizzled source chunk

  // fragment coords
  const int axor = lr & 7;
  const int arow_base = wm*128 + lr;
  const int brow_base = wn*64 + lr;

  f32x4 acc[8][4] = {};
  bf16x8 aR[4][2], bR0[2][2], bR1[2][2];

  // ---- prologue: tile0 -> buf0 (4 halves), tile1 -> buf1 (B h0,h1 + A h0)
  STAGE(xb,  LDS_A0, brow, 0, 0);  STAGE(xb,  LDS_A0, brow, 0, 1);
  STAGE(w1t, LDS_B0, bcol, 0, 0);  STAGE(w1t, LDS_B0, bcol, 0, 1);
  STAGE(w1t, LDS_B1, bcol, 1, 0);  STAGE(w1t, LDS_B1, bcol, 1, 1);
  STAGE(xb,  LDS_A1, brow, 1, 0);
  WAIT_VM6();            // 14 loads issued, <=6 outstanding -> tile0 landed
  BAR();

  // 8 full double-buffered iterations over tiles 0..15; tile 16 handled in tail.
  for (int i = 0; i < 8; ++i){
    const int c1 = 2*i + 1;
    const int n0 = 2*i + 2;                          // <= 16, real tile
    const int n1 = (2*i + 3 <= 16) ? 2*i + 3 : 16;   // i=7: redundant re-stage of 16, benign

    // ph1: read A0(mh0) + ALL B0; stage A1.h1 (tile c1)
    LDA_(LDS_A0, 0); LDB_(LDS_B0, 0, bR0); LDB_(LDS_B0, 1, bR1);
    STAGE(xb, LDS_A1, brow, c1, 1);
    BAR(); WAIT_LGKM0();
    MMA(0, 0, bR0);
    BAR();
    // ph2: stage B0.h0 (tile n0; B0 region free after ph1)
    STAGE(w1t, LDS_B0, bcol, n0, 0);
    BAR();
    MMA(0, 1, bR1);
    BAR();
    // ph3: read A0(mh1); stage B0.h1
    LDA_(LDS_A0, 1);
    STAGE(w1t, LDS_B0, bcol, n0, 1);
    BAR(); WAIT_LGKM0();
    MMA(1, 0, bR0);
    BAR();
    // ph4: stage A0.h0; counted vmcnt -> tile c1 landed
    STAGE(xb, LDS_A0, brow, n0, 0);
    WAIT_VM6();
    BAR();
    MMA(1, 1, bR1);
    BAR();
    // ph5: read A1(mh0) + ALL B1 (tile c1); stage A0.h1
    LDA_(LDS_A1, 0); LDB_(LDS_B1, 0, bR0); LDB_(LDS_B1, 1, bR1);
    STAGE(xb, LDS_A0, brow, n0, 1);
    BAR(); WAIT_LGKM0();
    MMA(0, 0, bR0);
    BAR();
    // ph6: stage B1.h0 (tile n1)
    STAGE(w1t, LDS_B1, bcol, n1, 0);
    BAR();
    MMA(0, 1, bR1);
    BAR();
    // ph7: read A1(mh1); stage B1.h1
    LDA_(LDS_A1, 1);
    STAGE(w1t, LDS_B1, bcol, n1, 1);
    BAR(); WAIT_LGKM0();
    MMA(1, 0, bR0);
    BAR();
    // ph8: stage A1.h0; counted vmcnt -> tile n0 landed
    STAGE(xb, LDS_A1, brow, n1, 0);
    WAIT_VM6();
    BAR();
    MMA(1, 1, bR1);
    BAR();
  }

  // ---- tail: tile 16 resides in A0/B0 (staged during i=7; landing guaranteed by
  // i=7 ph8's vmcnt(6): the A0.h1 pair is oldest-2 of the last 8 issued loads).
  // Barrier-free: every ds_read is consumed by an MFMA before this wave's next barrier.
  LDA_(LDS_A0, 0); LDB_(LDS_B0, 0, bR0); LDB_(LDS_B0, 1, bR1);
  MMA(0, 0, bR0); MMA(0, 1, bR1);
  LDA_(LDS_A0, 1);
  MMA(1, 0, bR0); MMA(1, 1, bR1);

  // ---- fused epilogue ----
  // Batch 1 of W2 fragments (ks 0..3): issue now, latency hides under silu/ds_writes.
  bf16x8 w2fA[4][4];
  #pragma unroll
  for (int ks = 0; ks < 4; ++ks)
    #pragma unroll
    for (int ni = 0; ni < 4; ++ni)
      w2fA[ks][ni] = *(const bf16x8*)(w2t + (size_t)(ni*16 + lr) * HID + bcol + ks*32 + lg*8);

  // Drain pending (clamped) prefetches before reusing LDS, then sync.
  WAIT_VM0();
  BAR();

  float b1v[4];
  #pragma unroll
  for (int ni = 0; ni < 4; ++ni) b1v[ni] = b1[bcol + wn*64 + ni*16 + lr];

  // silu + pack to bf16; scatter into LDS as [row 256][col 256] with chunk-XOR swizzle
  #pragma unroll
  for (int mi = 0; mi < 8; ++mi){
    #pragma unroll
    for (int ni = 0; ni < 4; ++ni){
      const int col = wn*64 + ni*16 + lr;
      #pragma unroll
      for (int i2 = 0; i2 < 4; ++i2){
        const int row = wm*128 + mi*16 + lg*4 + i2;
        float v = acc[mi][ni][i2] + b1v[ni];
        float s = v / (1.0f + __expf(-v));     // silu
        const int chunk = (col >> 3) ^ (row & 7);
        lds[row*256 + chunk*8 + (col & 7)] = f2bf(s);
      }
    }
  }
  __syncthreads();

  // Batch 2 of W2 fragments (ks 4..7): latency hides under first 4 ks of MFMA.
  bf16x8 w2fB[4][4];
  #pragma unroll
  for (int ks = 0; ks < 4; ++ks)
    #pragma unroll
    for (int ni = 0; ni < 4; ++ni)
      w2fB[ks][ni] = *(const bf16x8*)(w2t + (size_t)(ni*16 + lr) * HID + bcol + (ks+4)*32 + lg*8);

  // mini-GEMM: partial[r][n] = hTile[r][:256] @ W2chunk[:256][n], n in [0,64)
  const int rb = wid * 32;
  f32x4 acc2[2][4] = {};
  #pragma unroll
  for (int ks = 0; ks < 8; ++ks){
    bf16x8 a2[2];
    #pragma unroll
    for (int m = 0; m < 2; ++m){
      const int row = rb + m*16 + lr;
      a2[m] = *(const bf16x8*)(lds + row*256 + (((ks*4+lg) ^ (lr & 7)) << 3));
    }
    #pragma unroll
    for (int m = 0; m < 2; ++m)
      #pragma unroll
      for (int ni = 0; ni < 4; ++ni)
        acc2[m][ni] = __builtin_amdgcn_mfma_f32_16x16x32_bf16(
            a2[m], (ks < 4) ? w2fA[ks & 3][ni] : w2fB[ks & 3][ni], acc2[m][ni], 0, 0, 0);
  }

  // store partials: pbuf[cb][row][col]
  const int cb = bcol >> 8;
  #pragma unroll
  for (int m = 0; m < 2; ++m)
    #pragma unroll
    for (int ni = 0; ni < 4; ++ni)
      #pragma unroll
      for (int i2 = 0; i2 < 4; ++i2){
        const int r = brow + rb + m*16 + lg*4 + i2;
        pbuf[((size_t)cb << 21) + ((size_t)r << 6) + ni*16 + lr] = acc2[m][ni][i2];
      }
}

// ---------------- reduce: sum partials + b2 -> log-softmax -> NLL ----------------
__global__ __launch_bounds__(256) void k_red(const float* __restrict__ pbuf,
                                             const float* __restrict__ b2,
                                             const int* __restrict__ tgt,
                                             float* __restrict__ loss)
{
  const int lane = threadIdx.x & 63, w = threadIdx.x >> 6;
  const int row0 = blockIdx.x * 128 + w * 32;
  const float bias = (lane < 37) ? b2[lane] : 0.0f;
  for (int i = 0; i < 32; ++i){
    const int r = row0 + i;
    float s = 0.0f;
    #pragma unroll
    for (int cb = 0; cb < 8; ++cb)
      s += pbuf[((size_t)cb << 21) + ((size_t)r << 6) + lane];
    float x = (lane < 37) ? (s + bias) : -1e30f;
    float m = x;
    #pragma unroll
    for (int off = 1; off < 64; off <<= 1) m = fmaxf(m, __shfl_xor(m, off, 64));
    float e = __expf(x - m);
    float se = e;
    #pragma unroll
    for (int off = 1; off < 64; off <<= 1) se += __shfl_xor(se, off, 64);
    const int tg = tgt[r];
    const float pick = __shfl(x, tg, 64);
    if (lane == 0) loss[r] = m + __logf(se) - pick;
  }
}

// ---------------- launch ----------------
extern "C" void kernel_launch(void* const* d_in, const int* in_sizes, int n_in,
                              void* d_out, int out_size, void* d_ws, size_t ws_size,
                              hipStream_t stream)
{
  (void)in_sizes; (void)n_in; (void)out_size; (void)ws_size;
  const float* fc  = (const float*)d_in[0];
  const float* cam = (const float*)d_in[1];
  const float* ru  = (const float*)d_in[2];
  const float* W1  = (const float*)d_in[3];
  const float* b1  = (const float*)d_in[4];
  const float* W2  = (const float*)d_in[5];
  const float* b2  = (const float*)d_in[6];
  const int* afb = (const int*)d_in[7];
  const int* alr = (const int*)d_in[8];
  const int* ajp = (const int*)d_in[9];
  const int* ass = (const int*)d_in[10];
  const int* aat = (const int*)d_in[11];
  float* loss = (float*)d_out;

  // workspace layout (bytes):
  // xb   : 32768 x 1088 bf16  = 71,303,168
  // w1t  : 2048 x 1088 bf16   =  4,456,448
  // w2t  : 64 x 2048 bf16     =    262,144
  // tgt  : 32768 int32        =    131,072
  // pbuf : 8 x 32768 x 64 f32 = 67,108,864   (total ~136.6 MiB)
  char* ws = (char*)d_ws;
  unsigned short* xb  = (unsigned short*)(ws);
  unsigned short* w1t = (unsigned short*)(ws + 71303168);
  unsigned short* w2t = (unsigned short*)(ws + 75759616);
  int*            tgt = (int*)           (ws + 76021760);
  float*          pbuf= (float*)         (ws + 76152832);

  // fused prep: fc(16384) + w1t(8704) + w2t(512) + disc(128) = 25728 blocks
  k_prep<<<25728, 256, 0, stream>>>(fc, W1, W2, cam, ru, afb, alr, ajp, ass, aat,
                                    xb, w1t, w2t, tgt);
  k_gemm1<<<(B_ROWS/256) * (HID/256), 512, 0, stream>>>(xb, w1t, w2t, b1, pbuf);
  k_red  <<<B_ROWS / 128, 256, 0, stream>>>(pbuf, b2, tgt, loss);
}